// Round 1
// baseline (221.396 us; speedup 1.0000x reference)
//
#include <hip/hip_runtime.h>

#define N_NODES 100000
#define N_EDGES 3200000
#define IN_DIM 128
#define HID_DIM 64
#define OUT_DIM 2
#define N_GRAPHS 512

#define BSHIFT 6
#define NBUCK 1564         // ceil(100000/64)=1563, padded so NBUCK*NB3 % 1024 == 0
#define NB3 256            // blocks in hist/scatter passes
#define EPB 12500          // edges per block (256*12500 = 3.2M exact)
#define NSB 391            // scan blocks: 1564*256/1024
#define LDS_E2 3072        // per-bucket edge capacity (16-aligned lists incl. self slot)
#define ZERO_ROW N_NODES   // all-zero fp8 row used for alignment padding

// XCD-swizzled block column (NB3=256): blocks b, b+8, b+16.. (same XCD under
// %8 dispatch) get ADJACENT slots, so a 64B line is written by one XCD's L2.
__device__ inline int xcol(int b) { return ((b & 7) << 5) | (b >> 3); }

__device__ inline float uaf(unsigned int u) {
    union { unsigned int i; float f; } v; v.i = u; return v.f;
}
__device__ inline unsigned short f2bf(float f) {
    union { float f; unsigned int i; } v; v.f = f;
    unsigned int r = v.i + 0x7fffu + ((v.i >> 16) & 1u);
    return (unsigned short)(r >> 16);
}

typedef __attribute__((ext_vector_type(8))) short bf16x8;
typedef __attribute__((ext_vector_type(4))) float f32x4;
typedef __attribute__((ext_vector_type(2))) float f32x2;

// ---- pass 1: per-block LDS histogram over 1564 coarse buckets ------------
__global__ __launch_bounds__(512) void k_hist(const int* __restrict__ col,
                                              int* __restrict__ H) {
    __shared__ int h[NBUCK];
    for (int i = threadIdx.x; i < NBUCK; i += 512) h[i] = 0;
    __syncthreads();
    int b = blockIdx.x;
    int bb = xcol(b);
    int s = b * EPB, e = s + EPB;
    for (int i = s + threadIdx.x; i < e; i += 512)
        atomicAdd(&h[col[i] >> BSHIFT], 1);
    __syncthreads();
    for (int i = threadIdx.x; i < NBUCK; i += 512)
        H[i * NB3 + bb] = h[i];                   // bucket-major, swizzled col
}

// ---- pass 2a: local exclusive scan of the 400384-entry matrix ------------
__global__ __launch_bounds__(1024) void k_scan_a(const int* __restrict__ H,
                                                 int* __restrict__ OFF,
                                                 int* __restrict__ bsum) {
    __shared__ int lds[1024];
    int i = blockIdx.x * 1024 + threadIdx.x;
    int v = H[i];
    lds[threadIdx.x] = v;
    __syncthreads();
    for (int off = 1; off < 1024; off <<= 1) {
        int t = (threadIdx.x >= off) ? lds[threadIdx.x - off] : 0;
        __syncthreads();
        lds[threadIdx.x] += t;
        __syncthreads();
    }
    OFF[i] = lds[threadIdx.x] - v;
    if (threadIdx.x == 1023) bsum[blockIdx.x] = lds[1023];
}

// ---- pass 2b: finalize with block-sum prefix; zero gsum/gcnt + ZERO_ROW --
__global__ __launch_bounds__(1024) void k_scan_b(int* __restrict__ OFF,
                                                 const int* __restrict__ bsum,
                                                 float* __restrict__ gsum,
                                                 float* __restrict__ gcnt,
                                                 unsigned char* __restrict__ xws) {
    __shared__ int ls[NSB];
    for (int i = threadIdx.x; i < NSB; i += 1024) ls[i] = bsum[i];
    __syncthreads();
    if (threadIdx.x == 0) {
        int run = 0;
        for (int b = 0; b < NSB; b++) { int t = ls[b]; ls[b] = run; run += t; }
    }
    __syncthreads();
    int i = blockIdx.x * 1024 + threadIdx.x;
    OFF[i] += ls[blockIdx.x];
    // fused init work (replaces memsets)
    if (blockIdx.x < 32) gsum[blockIdx.x * 1024 + threadIdx.x] = 0.f;  // 32768 floats
    if (blockIdx.x == 33 && threadIdx.x < N_GRAPHS) gcnt[threadIdx.x] = 0.f;
    if (blockIdx.x == 32 && threadIdx.x < 16)
        ((int*)(xws + (size_t)ZERO_ROW * HID_DIM))[threadIdx.x] = 0;
}

// ---- pass 3: scatter packed edges into bucket-sorted order ---------------
// pk = (col & 63) << 17 | row  (row < 2^17). NB3=256 -> per (block,bucket)
// runs ~8 ints = 32B; swizzled columns keep line-sharing intra-XCD.
__global__ __launch_bounds__(512) void k_scatter(const int* __restrict__ row,
                                                 const int* __restrict__ col,
                                                 const int* __restrict__ OFF,
                                                 int* __restrict__ binned) {
    __shared__ int lofs[NBUCK];
    __shared__ int cur[NBUCK];
    int b = blockIdx.x;
    int bb = xcol(b);
    for (int i = threadIdx.x; i < NBUCK; i += 512) {
        lofs[i] = OFF[i * NB3 + bb];
        cur[i] = 0;
    }
    __syncthreads();
    int s = b * EPB, e = s + EPB;
    for (int i = s + threadIdx.x; i < e; i += 512) {
        int c = col[i];
        int r = row[i];
        int bk = c >> BSHIFT;
        int rk = atomicAdd(&cur[bk], 1);
        binned[lofs[bk] + rk] = ((c & 63) << 17) | r;
    }
}

// ---- per-node degree + dinv from the binned array (LDS-local counts) -----
__global__ __launch_bounds__(256) void k_deg(const int* __restrict__ binned,
                                             const int* __restrict__ OFF,
                                             int* __restrict__ degs,
                                             float* __restrict__ dinv) {
    int bkt = blockIdx.x;
    int s = OFF[bkt * NB3];
    int e = (bkt == NBUCK - 1) ? N_EDGES : OFF[(bkt + 1) * NB3];
    __shared__ int cnt[64];
    if (threadIdx.x < 64) cnt[threadIdx.x] = 0;
    __syncthreads();
    for (int i = s + threadIdx.x; i < e; i += 256)
        atomicAdd(&cnt[binned[i] >> 17], 1);
    __syncthreads();
    int n = (bkt << BSHIFT) + threadIdx.x;
    if (threadIdx.x < 64 && n < N_NODES) {
        degs[n] = cnt[threadIdx.x];
        dinv[n] = rsqrtf((float)cnt[threadIdx.x] + 1.0f);
    }
}

// ---- xws = (x @ W_gcn) * dinv via MFMA, output fp8 e4m3 ------------------
// Wave computes 16-node x 64-col tile with mfma_f32_16x16x32_bf16.
// A straight from global (two float4/K-step); B packed once into LDS frag
// table then held in VGPRs. C/D: col=lane&15, row=quad*4+reg. Epilogue:
// scale by dinv, pack to fp8 via v_cvt_pk_fp8_f32, 4 byte-stores per row.
__global__ __launch_bounds__(256) void k_gemm(const float* __restrict__ x,
                                              const float* __restrict__ Wg,
                                              const float* __restrict__ dinv,
                                              unsigned char* __restrict__ xws) {
    __shared__ unsigned short wb[16][64][8];   // [ks*4+nt][lane][j]  16 KB

    for (int idx = threadIdx.x; idx < 1024; idx += 256) {
        int f = idx >> 6, l = idx & 63;
        int ks = f >> 2, nt = f & 3;
        int n = (l & 15) + (nt << 4);
        int kbase = (ks << 5) + ((l >> 4) << 3);
        unsigned short tmp[8];
#pragma unroll
        for (int j = 0; j < 8; j++)
            tmp[j] = f2bf(Wg[(kbase + j) * HID_DIM + n]);
        *(bf16x8*)&wb[f][l][0] = *(const bf16x8*)tmp;
    }
    __syncthreads();

    int wave = threadIdx.x >> 6;
    int lane = threadIdx.x & 63;
    int q = lane >> 4, nn = lane & 15;

    bf16x8 bfrag[4][4];
#pragma unroll
    for (int ks = 0; ks < 4; ks++)
#pragma unroll
        for (int nt = 0; nt < 4; nt++)
            bfrag[ks][nt] = *(const bf16x8*)&wb[ks * 4 + nt][lane][0];

    int node0 = blockIdx.x * 64 + wave * 16;   // grid 1563: last block tail
    int arow = node0 + nn;
    if (arow > N_NODES - 1) arow = N_NODES - 1;   // clamp (stores predicated)
    const float* xrow = x + (size_t)arow * IN_DIM + (q << 3);

    f32x4 acc[4] = {{0.f,0.f,0.f,0.f},{0.f,0.f,0.f,0.f},
                    {0.f,0.f,0.f,0.f},{0.f,0.f,0.f,0.f}};
#pragma unroll
    for (int ks = 0; ks < 4; ks++) {
        float4 xa = *(const float4*)(xrow + ks * 32);
        float4 xb_ = *(const float4*)(xrow + ks * 32 + 4);
        bf16x8 af;
        af[0] = (short)f2bf(xa.x); af[1] = (short)f2bf(xa.y);
        af[2] = (short)f2bf(xa.z); af[3] = (short)f2bf(xa.w);
        af[4] = (short)f2bf(xb_.x); af[5] = (short)f2bf(xb_.y);
        af[6] = (short)f2bf(xb_.z); af[7] = (short)f2bf(xb_.w);
#pragma unroll
        for (int nt = 0; nt < 4; nt++)
            acc[nt] = __builtin_amdgcn_mfma_f32_16x16x32_bf16(af, bfrag[ks][nt], acc[nt], 0, 0, 0);
    }

#pragma unroll
    for (int r = 0; r < 4; r++) {
        int mrow = node0 + q * 4 + r;
        if (mrow < N_NODES) {
            float dn = dinv[mrow];
            int p01 = __builtin_amdgcn_cvt_pk_fp8_f32(acc[0][r] * dn, acc[1][r] * dn, 0, false);
            int p23 = __builtin_amdgcn_cvt_pk_fp8_f32(acc[2][r] * dn, acc[3][r] * dn, 0, false);
            unsigned char* rp = xws + (size_t)mrow * HID_DIM + nn;
            rp[0]  = (unsigned char)(p01 & 0xff);
            rp[16] = (unsigned char)((p01 >> 8) & 0xff);
            rp[32] = (unsigned char)(p23 & 0xff);
            rp[48] = (unsigned char)((p23 >> 8) & 0xff);
        }
    }
}

// ---- fused local-CSR build + gather-aggregate + ReLU + mean-pool ---------
// 256-thread block per 64-node bucket (4 waves, ~17.5KB LDS -> 8 blocks/CU:
// ALL 1564 blocks co-resident in one dispatch round). srt holds BYTE
// offsets (row<<6). Octet gather: 8 lanes x dwordx2 cover one row; 8
// subsets process 2 edges (int2) per iter -> 16 edges/wave-iter with half
// the load instrs of the dword scheme. Packed f32x2 accumulators ->
// v_pk_add_f32. Self-loop folded into the list (first pad slot = own row;
// lists sized (cnt+16)&~15 so the slot always exists). Cross-subset
// combine via shfl_xor 8/16/32. Per-graph node counts accumulated here
// (gcnt) so k_mlp needs no binary search.
__global__ __launch_bounds__(256) void k_aggrf(const unsigned char* __restrict__ xws,
                                               const int* __restrict__ binned,
                                               const int* __restrict__ OFF,
                                               const int* __restrict__ degs,
                                               const int* __restrict__ batch,
                                               const float* __restrict__ bg,
                                               float* __restrict__ gsum,
                                               float* __restrict__ gcnt) {
    int bkt = blockIdx.x;
    int nbase = bkt << BSHIFT;
    if (nbase >= N_NODES) return;                 // uniform exit (pad bucket)
    int nnodes = N_NODES - nbase; if (nnodes > 64) nnodes = 64;
    int s = OFF[bkt * NB3];
    int e = (bkt == NBUCK - 1) ? N_EDGES : OFF[(bkt + 1) * NB3];
    int m = e - s;

    __shared__ int cnt[64];
    __shared__ int lptr[65];
    __shared__ int cur[64];
    __shared__ int sb[64];
    __shared__ float gcl[8];
    __shared__ alignas(16) int srt[LDS_E2];
    __shared__ float pool[4][4][64];   // [wave][graph-slot][col]

    if (threadIdx.x < 64) {
        int n = nbase + threadIdx.x;
        cnt[threadIdx.x] = (threadIdx.x < nnodes) ? degs[n] : 0;
        sb[threadIdx.x]  = (threadIdx.x < nnodes) ? batch[n] : 0;
        cur[threadIdx.x] = 0;
    }
    if (threadIdx.x < 8) gcl[threadIdx.x] = 0.f;
    for (int t = threadIdx.x; t < 4 * 4 * 64; t += 256)
        ((float*)pool)[t] = 0.f;
    __syncthreads();

    // wave-parallel 16-aligned inclusive scan (wave 0); +1 slot for self
    if (threadIdx.x < 64) {
        int v = (cnt[threadIdx.x] + 16) & ~15;
        int run = v;
#pragma unroll
        for (int off = 1; off < 64; off <<= 1) {
            int t = __shfl_up(run, off);
            if (threadIdx.x >= off) run += t;
        }
        lptr[threadIdx.x + 1] = run;
        if (threadIdx.x == 0) lptr[0] = 0;
    }
    __syncthreads();
    int tot = lptr[64]; if (tot > LDS_E2) tot = LDS_E2;
    for (int i = threadIdx.x; i < tot; i += 256) srt[i] = ZERO_ROW << 6;
    __syncthreads();
    // self slot (right after the node's edges) + per-graph node counts
    if (threadIdx.x < nnodes) {
        int p = lptr[threadIdx.x] + cnt[threadIdx.x];
        if (p < LDS_E2) srt[p] = (nbase + threadIdx.x) << 6;
        int sl = sb[threadIdx.x] - sb[0];
        if (sl < 8) atomicAdd(&gcl[sl], 1.0f);
        else atomicAdd(&gcnt[sb[threadIdx.x]], 1.0f);
    }
    for (int i = threadIdx.x; i < m; i += 256) {
        int pk = binned[s + i];
        int nid = pk >> 17;
        int rk = atomicAdd(&cur[nid], 1);
        int pos = lptr[nid] + rk;
        if (pos < LDS_E2) srt[pos] = (pk & 0x1FFFF) << 6;   // byte offset
    }
    __syncthreads();

    int wave = threadIdx.x >> 6;
    int lane = threadIdx.x & 63;
    int sub = lane >> 3;                // subset: which edge pair
    int lc  = lane & 7;                 // lane-in-subset: cols 8lc..8lc+7
    int l8  = lc << 3;                  // byte offset of that qword in a row
    const unsigned char* xbl = xws + l8;
    int g0 = sb[0];
    float4 bia0, bia1;
    { const float4* bgv = (const float4*)bg;
      bia0 = bgv[lc * 2]; bia1 = bgv[lc * 2 + 1]; }

    for (int k = 0; k < 16; k++) {
        int ln = wave * 16 + k;
        if (ln >= nnodes) break;
        int s0 = lptr[ln], e0 = lptr[ln + 1];
        if (s0 > LDS_E2) s0 = LDS_E2;
        if (e0 > LDS_E2) e0 = LDS_E2;               // both multiples of 16
        f32x2 a0 = {0.f,0.f}, a1 = {0.f,0.f}, a2 = {0.f,0.f}, a3 = {0.f,0.f};
        for (int i = s0; i < e0; i += 16) {          // 16 slots / wave-iter
            int2 rr = *(const int2*)&srt[i + (sub << 1)];
            uint2 q0 = *(const uint2*)(xbl + rr.x);
            uint2 q1 = *(const uint2*)(xbl + rr.y);
            f32x2 p;
            p = __builtin_amdgcn_cvt_pk_f32_fp8(q0.x, false); a0 += p;
            p = __builtin_amdgcn_cvt_pk_f32_fp8(q0.x, true);  a1 += p;
            p = __builtin_amdgcn_cvt_pk_f32_fp8(q0.y, false); a2 += p;
            p = __builtin_amdgcn_cvt_pk_f32_fp8(q0.y, true);  a3 += p;
            p = __builtin_amdgcn_cvt_pk_f32_fp8(q1.x, false); a0 += p;
            p = __builtin_amdgcn_cvt_pk_f32_fp8(q1.x, true);  a1 += p;
            p = __builtin_amdgcn_cvt_pk_f32_fp8(q1.y, false); a2 += p;
            p = __builtin_amdgcn_cvt_pk_f32_fp8(q1.y, true);  a3 += p;
        }
        float r0 = a0[0], r1 = a0[1], r2 = a1[0], r3 = a1[1];
        float r4 = a2[0], r5 = a2[1], r6 = a3[0], r7 = a3[1];
#define RED8(x) x += __shfl_xor(x, 8); x += __shfl_xor(x, 16); x += __shfl_xor(x, 32);
        RED8(r0) RED8(r1) RED8(r2) RED8(r3) RED8(r4) RED8(r5) RED8(r6) RED8(r7)
#undef RED8
        if (sub == 0) {                 // lanes 0..7 own cols 8lc..8lc+7
            float dn = rsqrtf((float)cnt[ln] + 1.0f);
            float4 v0, v1;
            v0.x = fmaxf(r0 * dn + bia0.x, 0.f);
            v0.y = fmaxf(r1 * dn + bia0.y, 0.f);
            v0.z = fmaxf(r2 * dn + bia0.z, 0.f);
            v0.w = fmaxf(r3 * dn + bia0.w, 0.f);
            v1.x = fmaxf(r4 * dn + bia1.x, 0.f);
            v1.y = fmaxf(r5 * dn + bia1.y, 0.f);
            v1.z = fmaxf(r6 * dn + bia1.z, 0.f);
            v1.w = fmaxf(r7 * dn + bia1.w, 0.f);
            int slot = sb[ln] - g0;
            if (slot < 4) {
                float4* pp = (float4*)&pool[wave][slot][l8];
                float4 p0 = pp[0], p1 = pp[1];
                p0.x += v0.x; p0.y += v0.y; p0.z += v0.z; p0.w += v0.w;
                p1.x += v1.x; p1.y += v1.y; p1.z += v1.z; p1.w += v1.w;
                pp[0] = p0; pp[1] = p1;
            } else {                                // rare: >4 graphs in window
                float* gp = &gsum[sb[ln] * HID_DIM + l8];
                atomicAdd(gp + 0, v0.x); atomicAdd(gp + 1, v0.y);
                atomicAdd(gp + 2, v0.z); atomicAdd(gp + 3, v0.w);
                atomicAdd(gp + 4, v1.x); atomicAdd(gp + 5, v1.y);
                atomicAdd(gp + 6, v1.z); atomicAdd(gp + 7, v1.w);
            }
        }
    }
    __syncthreads();

    if (threadIdx.x < 8) {
        float c = gcl[threadIdx.x];
        if (c != 0.f) atomicAdd(&gcnt[g0 + threadIdx.x], c);
    }
    for (int t = threadIdx.x; t < 4 * 64; t += 256) {
        int slot = t >> 6, j = t & 63;
        float v = pool[0][slot][j] + pool[1][slot][j]
                + pool[2][slot][j] + pool[3][slot][j];
        if (v != 0.f) atomicAdd(&gsum[(g0 + slot) * HID_DIM + j], v);
    }
}

// ---- divide by counts + MLP + sigmoid (one wave per graph) ---------------
__global__ __launch_bounds__(64) void k_mlp(const float* __restrict__ gsum,
                                            const float* __restrict__ gcnt,
                                            const float* __restrict__ W1,
                                            const float* __restrict__ b1,
                                            const float* __restrict__ W2,
                                            const float* __restrict__ b2,
                                            float* __restrict__ out) {
    int g = blockIdx.x;
    int j = threadIdx.x;
    float cnt = fmaxf(gcnt[g], 1.0f);

    __shared__ float gs[64];
    __shared__ float hs[64];
    gs[j] = gsum[g * 64 + j] / cnt;
    __syncthreads();

    float h = b1[j];
    for (int k = 0; k < 64; k++) h += gs[k] * W1[k * 64 + j];
    hs[j] = fmaxf(h, 0.f);
    __syncthreads();

    if (j < OUT_DIM) {
        float o = b2[j];
        for (int k = 0; k < 64; k++) o += hs[k] * W2[k * OUT_DIM + j];
        out[g * OUT_DIM + j] = 1.f / (1.f + expf(-o));
    }
}

extern "C" void kernel_launch(void* const* d_in, const int* in_sizes, int n_in,
                              void* d_out, int out_size, void* d_ws, size_t ws_size,
                              hipStream_t stream) {
    const float* x   = (const float*)d_in[0];
    const int* eidx  = (const int*)d_in[1];
    const int* batch = (const int*)d_in[2];
    const float* Wg  = (const float*)d_in[3];
    const float* bg  = (const float*)d_in[4];
    const float* W1  = (const float*)d_in[5];
    const float* b1  = (const float*)d_in[6];
    const float* W2  = (const float*)d_in[7];
    const float* b2  = (const float*)d_in[8];
    float* out = (float*)d_out;

    // workspace layout (~24 MB)
    char* w = (char*)d_ws;
    unsigned char* xws = (unsigned char*)w;     w += (size_t)(N_NODES + 1) * HID_DIM;    // 6.4 MB (fp8)
    int*   binned  = (int*)w;                   w += (size_t)N_EDGES * 4;                // 12.8 MB
    int*   H       = (int*)w;                   w += (size_t)NBUCK * NB3 * 4;            // 1.6 MB
    int*   OFF     = (int*)w;                   w += (size_t)NBUCK * NB3 * 4;            // 1.6 MB
    int*   bsum    = (int*)w;                   w += NSB * 4;
    int*   degs    = (int*)w;                   w += N_NODES * 4;
    float* dinv    = (float*)w;                 w += N_NODES * 4;
    float* gsum    = (float*)w;                 w += N_GRAPHS * HID_DIM * 4;             // 131 KB
    float* gcnt    = (float*)w;                 w += N_GRAPHS * 4;                       // 2 KB

    const int* rowp = eidx;             // edge_index[0] (sources)
    const int* colp = eidx + N_EDGES;   // edge_index[1] (destinations)

    k_hist<<<NB3, 512, 0, stream>>>(colp, H);
    k_scan_a<<<NSB, 1024, 0, stream>>>(H, OFF, bsum);
    k_scan_b<<<NSB, 1024, 0, stream>>>(OFF, bsum, gsum, gcnt, xws);
    k_scatter<<<NB3, 512, 0, stream>>>(rowp, colp, OFF, binned);
    k_deg<<<NBUCK, 256, 0, stream>>>(binned, OFF, degs, dinv);
    k_gemm<<<(N_NODES + 63) / 64, 256, 0, stream>>>(x, Wg, dinv, xws);
    k_aggrf<<<NBUCK, 256, 0, stream>>>(xws, binned, OFF, degs, batch, bg, gsum, gcnt);
    k_mlp<<<N_GRAPHS, 64, 0, stream>>>(gsum, gcnt, W1, b1, W2, b2, out);
}

// Round 2
// 203.749 us; speedup vs baseline: 1.0866x; 1.0866x over previous
//
#include <hip/hip_runtime.h>

#define N_NODES 100000
#define N_EDGES 3200000
#define IN_DIM 128
#define HID_DIM 64
#define OUT_DIM 2
#define N_GRAPHS 512

#define BSHIFT 6
#define NBUCK 1564         // ceil(100000/64)=1563, padded so NBUCK*NB3 % 1024 == 0
#define NB3 256            // blocks in hist/scatter passes
#define EPB 12500          // edges per block (256*12500 = 3.2M exact)
#define NSB 391            // scan blocks: 1564*256/1024
#define LDS_E2 2816        // per-bucket edge capacity (4-aligned lists: mean ~2270, >11 sd slack)
#define ZERO_ROW N_NODES   // all-zero fp8 row used for alignment padding

// XCD-swizzled block column (NB3=256): blocks b, b+8, b+16.. (same XCD under
// %8 dispatch) get ADJACENT slots, so a 64B line is written by one XCD's L2.
__device__ inline int xcol(int b) { return ((b & 7) << 5) | (b >> 3); }

__device__ inline float uaf(unsigned int u) {
    union { unsigned int i; float f; } v; v.i = u; return v.f;
}
__device__ inline unsigned short f2bf(float f) {
    union { float f; unsigned int i; } v; v.f = f;
    unsigned int r = v.i + 0x7fffu + ((v.i >> 16) & 1u);
    return (unsigned short)(r >> 16);
}

typedef __attribute__((ext_vector_type(8))) short bf16x8;
typedef __attribute__((ext_vector_type(4))) float f32x4;
typedef __attribute__((ext_vector_type(2))) float f32x2;

// ---- pass 1: per-block LDS histogram over 1564 coarse buckets ------------
__global__ __launch_bounds__(512) void k_hist(const int* __restrict__ col,
                                              int* __restrict__ H) {
    __shared__ int h[NBUCK];
    for (int i = threadIdx.x; i < NBUCK; i += 512) h[i] = 0;
    __syncthreads();
    int b = blockIdx.x;
    int bb = xcol(b);
    int s = b * EPB, e = s + EPB;
    for (int i = s + threadIdx.x; i < e; i += 512)
        atomicAdd(&h[col[i] >> BSHIFT], 1);
    __syncthreads();
    for (int i = threadIdx.x; i < NBUCK; i += 512)
        H[i * NB3 + bb] = h[i];                   // bucket-major, swizzled col
}

// ---- pass 2a: local exclusive scan of the 400384-entry matrix ------------
__global__ __launch_bounds__(1024) void k_scan_a(const int* __restrict__ H,
                                                 int* __restrict__ OFF,
                                                 int* __restrict__ bsum) {
    __shared__ int lds[1024];
    int i = blockIdx.x * 1024 + threadIdx.x;
    int v = H[i];
    lds[threadIdx.x] = v;
    __syncthreads();
    for (int off = 1; off < 1024; off <<= 1) {
        int t = (threadIdx.x >= off) ? lds[threadIdx.x - off] : 0;
        __syncthreads();
        lds[threadIdx.x] += t;
        __syncthreads();
    }
    OFF[i] = lds[threadIdx.x] - v;
    if (threadIdx.x == 1023) bsum[blockIdx.x] = lds[1023];
}

// ---- pass 2b: finalize with block-sum prefix; zero gsum/gcnt + ZERO_ROW --
__global__ __launch_bounds__(1024) void k_scan_b(int* __restrict__ OFF,
                                                 const int* __restrict__ bsum,
                                                 float* __restrict__ gsum,
                                                 float* __restrict__ gcnt,
                                                 unsigned char* __restrict__ xws) {
    __shared__ int ls[NSB];
    for (int i = threadIdx.x; i < NSB; i += 1024) ls[i] = bsum[i];
    __syncthreads();
    if (threadIdx.x == 0) {
        int run = 0;
        for (int b = 0; b < NSB; b++) { int t = ls[b]; ls[b] = run; run += t; }
    }
    __syncthreads();
    int i = blockIdx.x * 1024 + threadIdx.x;
    OFF[i] += ls[blockIdx.x];
    // fused init work (replaces memsets)
    if (blockIdx.x < 32) gsum[blockIdx.x * 1024 + threadIdx.x] = 0.f;  // 32768 floats
    if (blockIdx.x == 33 && threadIdx.x < N_GRAPHS) gcnt[threadIdx.x] = 0.f;
    if (blockIdx.x == 32 && threadIdx.x < 16)
        ((int*)(xws + (size_t)ZERO_ROW * HID_DIM))[threadIdx.x] = 0;
}

// ---- pass 3: scatter packed edges into bucket-sorted order ---------------
// pk = (col & 63) << 17 | row  (row < 2^17). NB3=256 -> per (block,bucket)
// runs ~8 ints = 32B; swizzled columns keep line-sharing intra-XCD.
__global__ __launch_bounds__(512) void k_scatter(const int* __restrict__ row,
                                                 const int* __restrict__ col,
                                                 const int* __restrict__ OFF,
                                                 int* __restrict__ binned) {
    __shared__ int lofs[NBUCK];
    __shared__ int cur[NBUCK];
    int b = blockIdx.x;
    int bb = xcol(b);
    for (int i = threadIdx.x; i < NBUCK; i += 512) {
        lofs[i] = OFF[i * NB3 + bb];
        cur[i] = 0;
    }
    __syncthreads();
    int s = b * EPB, e = s + EPB;
    for (int i = s + threadIdx.x; i < e; i += 512) {
        int c = col[i];
        int r = row[i];
        int bk = c >> BSHIFT;
        int rk = atomicAdd(&cur[bk], 1);
        binned[lofs[bk] + rk] = ((c & 63) << 17) | r;
    }
}

// ---- per-node degree + dinv from the binned array (LDS-local counts) -----
__global__ __launch_bounds__(256) void k_deg(const int* __restrict__ binned,
                                             const int* __restrict__ OFF,
                                             int* __restrict__ degs,
                                             float* __restrict__ dinv) {
    int bkt = blockIdx.x;
    int s = OFF[bkt * NB3];
    int e = (bkt == NBUCK - 1) ? N_EDGES : OFF[(bkt + 1) * NB3];
    __shared__ int cnt[64];
    if (threadIdx.x < 64) cnt[threadIdx.x] = 0;
    __syncthreads();
    for (int i = s + threadIdx.x; i < e; i += 256)
        atomicAdd(&cnt[binned[i] >> 17], 1);
    __syncthreads();
    int n = (bkt << BSHIFT) + threadIdx.x;
    if (threadIdx.x < 64 && n < N_NODES) {
        degs[n] = cnt[threadIdx.x];
        dinv[n] = rsqrtf((float)cnt[threadIdx.x] + 1.0f);
    }
}

// ---- xws = (x @ W_gcn) * dinv via MFMA, output fp8 e4m3 ------------------
// Wave computes 16-node x 64-col tile with mfma_f32_16x16x32_bf16.
// A straight from global (two float4/K-step); B packed once into LDS frag
// table then held in VGPRs. C/D: col=lane&15, row=quad*4+reg. Epilogue:
// scale by dinv, pack to fp8 via v_cvt_pk_fp8_f32, 4 byte-stores per row.
__global__ __launch_bounds__(256) void k_gemm(const float* __restrict__ x,
                                              const float* __restrict__ Wg,
                                              const float* __restrict__ dinv,
                                              unsigned char* __restrict__ xws) {
    __shared__ unsigned short wb[16][64][8];   // [ks*4+nt][lane][j]  16 KB

    for (int idx = threadIdx.x; idx < 1024; idx += 256) {
        int f = idx >> 6, l = idx & 63;
        int ks = f >> 2, nt = f & 3;
        int n = (l & 15) + (nt << 4);
        int kbase = (ks << 5) + ((l >> 4) << 3);
        unsigned short tmp[8];
#pragma unroll
        for (int j = 0; j < 8; j++)
            tmp[j] = f2bf(Wg[(kbase + j) * HID_DIM + n]);
        *(bf16x8*)&wb[f][l][0] = *(const bf16x8*)tmp;
    }
    __syncthreads();

    int wave = threadIdx.x >> 6;
    int lane = threadIdx.x & 63;
    int q = lane >> 4, nn = lane & 15;

    bf16x8 bfrag[4][4];
#pragma unroll
    for (int ks = 0; ks < 4; ks++)
#pragma unroll
        for (int nt = 0; nt < 4; nt++)
            bfrag[ks][nt] = *(const bf16x8*)&wb[ks * 4 + nt][lane][0];

    int node0 = blockIdx.x * 64 + wave * 16;   // grid 1563: last block tail
    int arow = node0 + nn;
    if (arow > N_NODES - 1) arow = N_NODES - 1;   // clamp (stores predicated)
    const float* xrow = x + (size_t)arow * IN_DIM + (q << 3);

    f32x4 acc[4] = {{0.f,0.f,0.f,0.f},{0.f,0.f,0.f,0.f},
                    {0.f,0.f,0.f,0.f},{0.f,0.f,0.f,0.f}};
#pragma unroll
    for (int ks = 0; ks < 4; ks++) {
        float4 xa = *(const float4*)(xrow + ks * 32);
        float4 xb_ = *(const float4*)(xrow + ks * 32 + 4);
        bf16x8 af;
        af[0] = (short)f2bf(xa.x); af[1] = (short)f2bf(xa.y);
        af[2] = (short)f2bf(xa.z); af[3] = (short)f2bf(xa.w);
        af[4] = (short)f2bf(xb_.x); af[5] = (short)f2bf(xb_.y);
        af[6] = (short)f2bf(xb_.z); af[7] = (short)f2bf(xb_.w);
#pragma unroll
        for (int nt = 0; nt < 4; nt++)
            acc[nt] = __builtin_amdgcn_mfma_f32_16x16x32_bf16(af, bfrag[ks][nt], acc[nt], 0, 0, 0);
    }

#pragma unroll
    for (int r = 0; r < 4; r++) {
        int mrow = node0 + q * 4 + r;
        if (mrow < N_NODES) {
            float dn = dinv[mrow];
            int p01 = __builtin_amdgcn_cvt_pk_fp8_f32(acc[0][r] * dn, acc[1][r] * dn, 0, false);
            int p23 = __builtin_amdgcn_cvt_pk_fp8_f32(acc[2][r] * dn, acc[3][r] * dn, 0, false);
            unsigned char* rp = xws + (size_t)mrow * HID_DIM + nn;
            rp[0]  = (unsigned char)(p01 & 0xff);
            rp[16] = (unsigned char)((p01 >> 8) & 0xff);
            rp[32] = (unsigned char)(p23 & 0xff);
            rp[48] = (unsigned char)((p23 >> 8) & 0xff);
        }
    }
}

// ---- fused local-CSR build + gather-aggregate + ReLU + mean-pool ---------
// 512-thread block per 64-node bucket. srt holds BYTE offsets (row<<6).
// Subset-per-node gather: each 16-lane subset owns ONE node and serially
// accumulates its whole list (lane lc owns cols 4lc..4lc+3 end-to-end) ->
// per-node epilogue needs ZERO cross-lane shuffles. 4 subsets process 4
// different nodes concurrently (divergent trip counts handled by exec
// mask, cost = max-of-4). Lists 4-aligned with the self-loop folded in as
// the first pad slot -> pad waste ~7% (was 26% at 16-align). Per-graph
// node counts (gcnt) accumulated here so k_mlp needs no binary search.
__global__ __launch_bounds__(512) void k_aggrf(const unsigned char* __restrict__ xws,
                                               const int* __restrict__ binned,
                                               const int* __restrict__ OFF,
                                               const int* __restrict__ degs,
                                               const int* __restrict__ batch,
                                               const float* __restrict__ bg,
                                               float* __restrict__ gsum,
                                               float* __restrict__ gcnt) {
    int bkt = blockIdx.x;
    int nbase = bkt << BSHIFT;
    if (nbase >= N_NODES) return;                 // uniform exit (pad bucket)
    int nnodes = N_NODES - nbase; if (nnodes > 64) nnodes = 64;
    int s = OFF[bkt * NB3];
    int e = (bkt == NBUCK - 1) ? N_EDGES : OFF[(bkt + 1) * NB3];
    int m = e - s;

    __shared__ int cnt[64];
    __shared__ int lptr[65];
    __shared__ int cur[64];
    __shared__ int sb[64];
    __shared__ float gcl[8];
    __shared__ alignas(16) int srt[LDS_E2];
    __shared__ float pool[8][4][64];   // [wave][graph-slot][col]

    if (threadIdx.x < 64) {
        int n = nbase + threadIdx.x;
        cnt[threadIdx.x] = (threadIdx.x < nnodes) ? degs[n] : 0;
        sb[threadIdx.x]  = (threadIdx.x < nnodes) ? batch[n] : 0;
        cur[threadIdx.x] = 0;
    }
    if (threadIdx.x < 8) gcl[threadIdx.x] = 0.f;
    for (int t = threadIdx.x; t < 8 * 4 * 64; t += 512)
        ((float*)pool)[t] = 0.f;
    __syncthreads();

    // wave-parallel 4-aligned inclusive scan (wave 0); +1 slot for self
    if (threadIdx.x < 64) {
        int v = (threadIdx.x < nnodes) ? ((cnt[threadIdx.x] + 4) & ~3) : 0;
        int run = v;
#pragma unroll
        for (int off = 1; off < 64; off <<= 1) {
            int t = __shfl_up(run, off);
            if (threadIdx.x >= off) run += t;
        }
        lptr[threadIdx.x + 1] = run;
        if (threadIdx.x == 0) lptr[0] = 0;
    }
    __syncthreads();
    int tot = lptr[64]; if (tot > LDS_E2) tot = LDS_E2;
    for (int i = threadIdx.x; i < tot; i += 512) srt[i] = ZERO_ROW << 6;
    __syncthreads();
    // self slot (right after the node's edges) + per-graph node counts
    if (threadIdx.x < nnodes) {
        int p = lptr[threadIdx.x] + cnt[threadIdx.x];
        if (p < LDS_E2) srt[p] = (nbase + threadIdx.x) << 6;
        int sl = sb[threadIdx.x] - sb[0];
        if (sl < 8) atomicAdd(&gcl[sl], 1.0f);
        else atomicAdd(&gcnt[sb[threadIdx.x]], 1.0f);
    }
    for (int i = threadIdx.x; i < m; i += 512) {
        int pk = binned[s + i];
        int nid = pk >> 17;
        int rk = atomicAdd(&cur[nid], 1);
        int pos = lptr[nid] + rk;
        if (pos < LDS_E2) srt[pos] = (pk & 0x1FFFF) << 6;   // byte offset
    }
    __syncthreads();

    int wave = threadIdx.x >> 6;
    int lane = threadIdx.x & 63;
    int sub = lane >> 4;                // subset: owns one node at a time
    int lc  = lane & 15;                // lane-in-subset: cols 4lc..4lc+3
    int l4  = lc << 2;                  // byte offset of that dword in a row
    const unsigned char* xbl = xws + l4;
    int g0 = sb[0];
    float4 bia = ((const float4*)bg)[lc];

#pragma unroll
    for (int r = 0; r < 2; r++) {
        int ln = wave * 8 + sub * 2 + r;          // 32 processors x 2 rounds
        int valid = (ln < nnodes);
        int s0 = valid ? lptr[ln] : 0;
        int e0 = valid ? lptr[ln + 1] : 0;
        if (s0 > LDS_E2) s0 = LDS_E2;
        if (e0 > LDS_E2) e0 = LDS_E2;             // both multiples of 4
        f32x2 alo = {0.f, 0.f}, ahi = {0.f, 0.f};
        for (int i = s0; i < e0; i += 4) {        // divergent across subsets
            int4 rr = *(const int4*)&srt[i];      // subset-uniform broadcast
            unsigned int d0 = *(const unsigned int*)(xbl + rr.x);
            unsigned int d1 = *(const unsigned int*)(xbl + rr.y);
            unsigned int d2 = *(const unsigned int*)(xbl + rr.z);
            unsigned int d3 = *(const unsigned int*)(xbl + rr.w);
            f32x2 p;
            p = __builtin_amdgcn_cvt_pk_f32_fp8(d0, false); alo += p;
            p = __builtin_amdgcn_cvt_pk_f32_fp8(d0, true);  ahi += p;
            p = __builtin_amdgcn_cvt_pk_f32_fp8(d1, false); alo += p;
            p = __builtin_amdgcn_cvt_pk_f32_fp8(d1, true);  ahi += p;
            p = __builtin_amdgcn_cvt_pk_f32_fp8(d2, false); alo += p;
            p = __builtin_amdgcn_cvt_pk_f32_fp8(d2, true);  ahi += p;
            p = __builtin_amdgcn_cvt_pk_f32_fp8(d3, false); alo += p;
            p = __builtin_amdgcn_cvt_pk_f32_fp8(d3, true);  ahi += p;
        }
        int slot = 99;
        float4 val;
        if (valid) {
            float dn = rsqrtf((float)cnt[ln] + 1.0f);
            val.x = fmaxf(alo[0] * dn + bia.x, 0.f);
            val.y = fmaxf(alo[1] * dn + bia.y, 0.f);
            val.z = fmaxf(ahi[0] * dn + bia.z, 0.f);
            val.w = fmaxf(ahi[1] * dn + bia.w, 0.f);
            slot = sb[ln] - g0;
        }
        // serialize the 4 subsets' pool RMW (same wave -> in-order LDS ops)
#pragma unroll
        for (int ss = 0; ss < 4; ss++) {
            if (sub == ss && slot < 4) {
                float4* pp = (float4*)&pool[wave][slot][l4];
                float4 pv = *pp;
                pv.x += val.x; pv.y += val.y; pv.z += val.z; pv.w += val.w;
                *pp = pv;
            }
        }
        if (slot >= 4 && slot < 99) {             // rare: >4 graphs in window
            float* gp = &gsum[sb[ln] * HID_DIM + l4];
            atomicAdd(gp + 0, val.x); atomicAdd(gp + 1, val.y);
            atomicAdd(gp + 2, val.z); atomicAdd(gp + 3, val.w);
        }
    }
    __syncthreads();

    if (threadIdx.x < 8) {
        float c = gcl[threadIdx.x];
        if (c != 0.f) atomicAdd(&gcnt[g0 + threadIdx.x], c);
    }
    for (int t = threadIdx.x; t < 4 * 64; t += 512) {
        int slot = t >> 6, j = t & 63;
        float v = 0.f;
#pragma unroll
        for (int w2 = 0; w2 < 8; w2++) v += pool[w2][slot][j];
        if (v != 0.f) atomicAdd(&gsum[(g0 + slot) * HID_DIM + j], v);
    }
}

// ---- divide by counts + MLP + sigmoid (one wave per graph) ---------------
__global__ __launch_bounds__(64) void k_mlp(const float* __restrict__ gsum,
                                            const float* __restrict__ gcnt,
                                            const float* __restrict__ W1,
                                            const float* __restrict__ b1,
                                            const float* __restrict__ W2,
                                            const float* __restrict__ b2,
                                            float* __restrict__ out) {
    int g = blockIdx.x;
    int j = threadIdx.x;
    float cnt = fmaxf(gcnt[g], 1.0f);

    __shared__ float gs[64];
    __shared__ float hs[64];
    gs[j] = gsum[g * 64 + j] / cnt;
    __syncthreads();

    float h = b1[j];
    for (int k = 0; k < 64; k++) h += gs[k] * W1[k * 64 + j];
    hs[j] = fmaxf(h, 0.f);
    __syncthreads();

    if (j < OUT_DIM) {
        float o = b2[j];
        for (int k = 0; k < 64; k++) o += hs[k] * W2[k * OUT_DIM + j];
        out[g * OUT_DIM + j] = 1.f / (1.f + expf(-o));
    }
}

extern "C" void kernel_launch(void* const* d_in, const int* in_sizes, int n_in,
                              void* d_out, int out_size, void* d_ws, size_t ws_size,
                              hipStream_t stream) {
    const float* x   = (const float*)d_in[0];
    const int* eidx  = (const int*)d_in[1];
    const int* batch = (const int*)d_in[2];
    const float* Wg  = (const float*)d_in[3];
    const float* bg  = (const float*)d_in[4];
    const float* W1  = (const float*)d_in[5];
    const float* b1  = (const float*)d_in[6];
    const float* W2  = (const float*)d_in[7];
    const float* b2  = (const float*)d_in[8];
    float* out = (float*)d_out;

    // workspace layout (~24 MB)
    char* w = (char*)d_ws;
    unsigned char* xws = (unsigned char*)w;     w += (size_t)(N_NODES + 1) * HID_DIM;    // 6.4 MB (fp8)
    int*   binned  = (int*)w;                   w += (size_t)N_EDGES * 4;                // 12.8 MB
    int*   H       = (int*)w;                   w += (size_t)NBUCK * NB3 * 4;            // 1.6 MB
    int*   OFF     = (int*)w;                   w += (size_t)NBUCK * NB3 * 4;            // 1.6 MB
    int*   bsum    = (int*)w;                   w += NSB * 4;
    int*   degs    = (int*)w;                   w += N_NODES * 4;
    float* dinv    = (float*)w;                 w += N_NODES * 4;
    float* gsum    = (float*)w;                 w += N_GRAPHS * HID_DIM * 4;             // 131 KB
    float* gcnt    = (float*)w;                 w += N_GRAPHS * 4;                       // 2 KB

    const int* rowp = eidx;             // edge_index[0] (sources)
    const int* colp = eidx + N_EDGES;   // edge_index[1] (destinations)

    k_hist<<<NB3, 512, 0, stream>>>(colp, H);
    k_scan_a<<<NSB, 1024, 0, stream>>>(H, OFF, bsum);
    k_scan_b<<<NSB, 1024, 0, stream>>>(OFF, bsum, gsum, gcnt, xws);
    k_scatter<<<NB3, 512, 0, stream>>>(rowp, colp, OFF, binned);
    k_deg<<<NBUCK, 256, 0, stream>>>(binned, OFF, degs, dinv);
    k_gemm<<<(N_NODES + 63) / 64, 256, 0, stream>>>(x, Wg, dinv, xws);
    k_aggrf<<<NBUCK, 512, 0, stream>>>(xws, binned, OFF, degs, batch, bg, gsum, gcnt);
    k_mlp<<<N_GRAPHS, 64, 0, stream>>>(gsum, gcnt, W1, b1, W2, b2, out);
}

// Round 3
// 201.151 us; speedup vs baseline: 1.1006x; 1.0129x over previous
//
#include <hip/hip_runtime.h>

#define N_NODES 100000
#define N_EDGES 3200000
#define IN_DIM 128
#define HID_DIM 64
#define OUT_DIM 2
#define N_GRAPHS 512

#define BSHIFT 6
#define NBUCK 1564         // ceil(100000/64)=1563, padded so NBUCK*NB3 % 1024 == 0
#define NB3 256            // blocks in hist/scatter passes
#define EPB 12500          // edges per block (256*12500 = 3.2M exact)
#define NSB 391            // scan blocks: 1564*256/1024
#define LDS_E2 2816        // per-bucket edge capacity (8-aligned lists: mean ~2336, ~10 sd slack)
#define ZERO_ROW N_NODES   // all-zero fp8 row used for alignment padding

// XCD-swizzled block column (NB3=256): blocks b, b+8, b+16.. (same XCD under
// %8 dispatch) get ADJACENT slots, so a 64B line is written by one XCD's L2.
__device__ inline int xcol(int b) { return ((b & 7) << 5) | (b >> 3); }

__device__ inline float uaf(unsigned int u) {
    union { unsigned int i; float f; } v; v.i = u; return v.f;
}
__device__ inline unsigned short f2bf(float f) {
    union { float f; unsigned int i; } v; v.f = f;
    unsigned int r = v.i + 0x7fffu + ((v.i >> 16) & 1u);
    return (unsigned short)(r >> 16);
}

typedef __attribute__((ext_vector_type(8))) short bf16x8;
typedef __attribute__((ext_vector_type(4))) float f32x4;
typedef __attribute__((ext_vector_type(2))) float f32x2;

// ---- pass 1: per-block LDS histogram over 1564 coarse buckets ------------
__global__ __launch_bounds__(512) void k_hist(const int* __restrict__ col,
                                              int* __restrict__ H) {
    __shared__ int h[NBUCK];
    for (int i = threadIdx.x; i < NBUCK; i += 512) h[i] = 0;
    __syncthreads();
    int b = blockIdx.x;
    int bb = xcol(b);
    int s = b * EPB, e = s + EPB;
    for (int i = s + threadIdx.x; i < e; i += 512)
        atomicAdd(&h[col[i] >> BSHIFT], 1);
    __syncthreads();
    for (int i = threadIdx.x; i < NBUCK; i += 512)
        H[i * NB3 + bb] = h[i];                   // bucket-major, swizzled col
}

// ---- pass 2a: local exclusive scan of the 400384-entry matrix ------------
__global__ __launch_bounds__(1024) void k_scan_a(const int* __restrict__ H,
                                                 int* __restrict__ OFF,
                                                 int* __restrict__ bsum) {
    __shared__ int lds[1024];
    int i = blockIdx.x * 1024 + threadIdx.x;
    int v = H[i];
    lds[threadIdx.x] = v;
    __syncthreads();
    for (int off = 1; off < 1024; off <<= 1) {
        int t = (threadIdx.x >= off) ? lds[threadIdx.x - off] : 0;
        __syncthreads();
        lds[threadIdx.x] += t;
        __syncthreads();
    }
    OFF[i] = lds[threadIdx.x] - v;
    if (threadIdx.x == 1023) bsum[blockIdx.x] = lds[1023];
}

// ---- pass 2b: finalize with block-sum prefix; zero gsum/gcnt + ZERO_ROW --
__global__ __launch_bounds__(1024) void k_scan_b(int* __restrict__ OFF,
                                                 const int* __restrict__ bsum,
                                                 float* __restrict__ gsum,
                                                 float* __restrict__ gcnt,
                                                 unsigned char* __restrict__ xws) {
    __shared__ int ls[NSB];
    for (int i = threadIdx.x; i < NSB; i += 1024) ls[i] = bsum[i];
    __syncthreads();
    if (threadIdx.x == 0) {
        int run = 0;
        for (int b = 0; b < NSB; b++) { int t = ls[b]; ls[b] = run; run += t; }
    }
    __syncthreads();
    int i = blockIdx.x * 1024 + threadIdx.x;
    OFF[i] += ls[blockIdx.x];
    // fused init work (replaces memsets)
    if (blockIdx.x < 32) gsum[blockIdx.x * 1024 + threadIdx.x] = 0.f;  // 32768 floats
    if (blockIdx.x == 33 && threadIdx.x < N_GRAPHS) gcnt[threadIdx.x] = 0.f;
    if (blockIdx.x == 32 && threadIdx.x < 16)
        ((int*)(xws + (size_t)ZERO_ROW * HID_DIM))[threadIdx.x] = 0;
}

// ---- pass 3: scatter packed edges into bucket-sorted order ---------------
// pk = (col & 63) << 17 | row  (row < 2^17). NB3=256 -> per (block,bucket)
// runs ~8 ints = 32B; swizzled columns keep line-sharing intra-XCD.
__global__ __launch_bounds__(512) void k_scatter(const int* __restrict__ row,
                                                 const int* __restrict__ col,
                                                 const int* __restrict__ OFF,
                                                 int* __restrict__ binned) {
    __shared__ int lofs[NBUCK];
    __shared__ int cur[NBUCK];
    int b = blockIdx.x;
    int bb = xcol(b);
    for (int i = threadIdx.x; i < NBUCK; i += 512) {
        lofs[i] = OFF[i * NB3 + bb];
        cur[i] = 0;
    }
    __syncthreads();
    int s = b * EPB, e = s + EPB;
    for (int i = s + threadIdx.x; i < e; i += 512) {
        int c = col[i];
        int r = row[i];
        int bk = c >> BSHIFT;
        int rk = atomicAdd(&cur[bk], 1);
        binned[lofs[bk] + rk] = ((c & 63) << 17) | r;
    }
}

// ---- per-node degree + dinv from the binned array (LDS-local counts) -----
__global__ __launch_bounds__(256) void k_deg(const int* __restrict__ binned,
                                             const int* __restrict__ OFF,
                                             int* __restrict__ degs,
                                             float* __restrict__ dinv) {
    int bkt = blockIdx.x;
    int s = OFF[bkt * NB3];
    int e = (bkt == NBUCK - 1) ? N_EDGES : OFF[(bkt + 1) * NB3];
    __shared__ int cnt[64];
    if (threadIdx.x < 64) cnt[threadIdx.x] = 0;
    __syncthreads();
    for (int i = s + threadIdx.x; i < e; i += 256)
        atomicAdd(&cnt[binned[i] >> 17], 1);
    __syncthreads();
    int n = (bkt << BSHIFT) + threadIdx.x;
    if (threadIdx.x < 64 && n < N_NODES) {
        degs[n] = cnt[threadIdx.x];
        dinv[n] = rsqrtf((float)cnt[threadIdx.x] + 1.0f);
    }
}

// ---- xws = (x @ W_gcn) * dinv via MFMA, output fp8 e4m3 ------------------
// Wave computes 16-node x 64-col tile with mfma_f32_16x16x32_bf16.
// A straight from global (two float4/K-step); B packed once into LDS frag
// table then held in VGPRs. C/D: col=lane&15, row=quad*4+reg. Epilogue:
// scale by dinv, pack to fp8 via v_cvt_pk_fp8_f32, 4 byte-stores per row.
__global__ __launch_bounds__(256) void k_gemm(const float* __restrict__ x,
                                              const float* __restrict__ Wg,
                                              const float* __restrict__ dinv,
                                              unsigned char* __restrict__ xws) {
    __shared__ unsigned short wb[16][64][8];   // [ks*4+nt][lane][j]  16 KB

    for (int idx = threadIdx.x; idx < 1024; idx += 256) {
        int f = idx >> 6, l = idx & 63;
        int ks = f >> 2, nt = f & 3;
        int n = (l & 15) + (nt << 4);
        int kbase = (ks << 5) + ((l >> 4) << 3);
        unsigned short tmp[8];
#pragma unroll
        for (int j = 0; j < 8; j++)
            tmp[j] = f2bf(Wg[(kbase + j) * HID_DIM + n]);
        *(bf16x8*)&wb[f][l][0] = *(const bf16x8*)tmp;
    }
    __syncthreads();

    int wave = threadIdx.x >> 6;
    int lane = threadIdx.x & 63;
    int q = lane >> 4, nn = lane & 15;

    bf16x8 bfrag[4][4];
#pragma unroll
    for (int ks = 0; ks < 4; ks++)
#pragma unroll
        for (int nt = 0; nt < 4; nt++)
            bfrag[ks][nt] = *(const bf16x8*)&wb[ks * 4 + nt][lane][0];

    int node0 = blockIdx.x * 64 + wave * 16;   // grid 1563: last block tail
    int arow = node0 + nn;
    if (arow > N_NODES - 1) arow = N_NODES - 1;   // clamp (stores predicated)
    const float* xrow = x + (size_t)arow * IN_DIM + (q << 3);

    f32x4 acc[4] = {{0.f,0.f,0.f,0.f},{0.f,0.f,0.f,0.f},
                    {0.f,0.f,0.f,0.f},{0.f,0.f,0.f,0.f}};
#pragma unroll
    for (int ks = 0; ks < 4; ks++) {
        float4 xa = *(const float4*)(xrow + ks * 32);
        float4 xb_ = *(const float4*)(xrow + ks * 32 + 4);
        bf16x8 af;
        af[0] = (short)f2bf(xa.x); af[1] = (short)f2bf(xa.y);
        af[2] = (short)f2bf(xa.z); af[3] = (short)f2bf(xa.w);
        af[4] = (short)f2bf(xb_.x); af[5] = (short)f2bf(xb_.y);
        af[6] = (short)f2bf(xb_.z); af[7] = (short)f2bf(xb_.w);
#pragma unroll
        for (int nt = 0; nt < 4; nt++)
            acc[nt] = __builtin_amdgcn_mfma_f32_16x16x32_bf16(af, bfrag[ks][nt], acc[nt], 0, 0, 0);
    }

#pragma unroll
    for (int r = 0; r < 4; r++) {
        int mrow = node0 + q * 4 + r;
        if (mrow < N_NODES) {
            float dn = dinv[mrow];
            int p01 = __builtin_amdgcn_cvt_pk_fp8_f32(acc[0][r] * dn, acc[1][r] * dn, 0, false);
            int p23 = __builtin_amdgcn_cvt_pk_fp8_f32(acc[2][r] * dn, acc[3][r] * dn, 0, false);
            unsigned char* rp = xws + (size_t)mrow * HID_DIM + nn;
            rp[0]  = (unsigned char)(p01 & 0xff);
            rp[16] = (unsigned char)((p01 >> 8) & 0xff);
            rp[32] = (unsigned char)(p23 & 0xff);
            rp[48] = (unsigned char)((p23 >> 8) & 0xff);
        }
    }
}

// ---- fused local-CSR build + gather-aggregate + ReLU + mean-pool ---------
// 512-thread block per 64-node bucket. srt holds BYTE offsets (row<<6).
// Subset-per-node gather: each 16-lane subset owns ONE node and serially
// accumulates its whole list (lane lc owns cols 4lc..4lc+3 end-to-end) ->
// per-node epilogue needs ZERO cross-lane shuffles. Lists 8-ALIGNED with
// the self-loop folded in as the first pad slot; the gather is unrolled
// 8 slots/iter (2x ds_read_b128 + 8 row-loads in flight per wave) with 4
// independent accumulator chains -> 2x memory-level parallelism vs the
// 4-slot loop (latency-bound kernel: concurrency is the knob). Per-graph
// node counts (gcnt) accumulated here so k_mlp needs no binary search.
__global__ __launch_bounds__(512) void k_aggrf(const unsigned char* __restrict__ xws,
                                               const int* __restrict__ binned,
                                               const int* __restrict__ OFF,
                                               const int* __restrict__ degs,
                                               const int* __restrict__ batch,
                                               const float* __restrict__ bg,
                                               float* __restrict__ gsum,
                                               float* __restrict__ gcnt) {
    int bkt = blockIdx.x;
    int nbase = bkt << BSHIFT;
    if (nbase >= N_NODES) return;                 // uniform exit (pad bucket)
    int nnodes = N_NODES - nbase; if (nnodes > 64) nnodes = 64;
    int s = OFF[bkt * NB3];
    int e = (bkt == NBUCK - 1) ? N_EDGES : OFF[(bkt + 1) * NB3];
    int m = e - s;

    __shared__ int cnt[64];
    __shared__ int lptr[65];
    __shared__ int cur[64];
    __shared__ int sb[64];
    __shared__ float gcl[8];
    __shared__ alignas(16) int srt[LDS_E2];
    __shared__ float pool[8][4][64];   // [wave][graph-slot][col]

    if (threadIdx.x < 64) {
        int n = nbase + threadIdx.x;
        cnt[threadIdx.x] = (threadIdx.x < nnodes) ? degs[n] : 0;
        sb[threadIdx.x]  = (threadIdx.x < nnodes) ? batch[n] : 0;
        cur[threadIdx.x] = 0;
    }
    if (threadIdx.x < 8) gcl[threadIdx.x] = 0.f;
    for (int t = threadIdx.x; t < 8 * 4 * 64; t += 512)
        ((float*)pool)[t] = 0.f;
    __syncthreads();

    // wave-parallel 8-aligned inclusive scan (wave 0); +1 slot for self
    if (threadIdx.x < 64) {
        int v = (threadIdx.x < nnodes) ? ((cnt[threadIdx.x] + 8) & ~7) : 0;
        int run = v;
#pragma unroll
        for (int off = 1; off < 64; off <<= 1) {
            int t = __shfl_up(run, off);
            if (threadIdx.x >= off) run += t;
        }
        lptr[threadIdx.x + 1] = run;
        if (threadIdx.x == 0) lptr[0] = 0;
    }
    __syncthreads();
    int tot = lptr[64]; if (tot > LDS_E2) tot = LDS_E2;
    for (int i = threadIdx.x; i < tot; i += 512) srt[i] = ZERO_ROW << 6;
    __syncthreads();
    // self slot (right after the node's edges) + per-graph node counts
    if (threadIdx.x < nnodes) {
        int p = lptr[threadIdx.x] + cnt[threadIdx.x];
        if (p < LDS_E2) srt[p] = (nbase + threadIdx.x) << 6;
        int sl = sb[threadIdx.x] - sb[0];
        if (sl < 8) atomicAdd(&gcl[sl], 1.0f);
        else atomicAdd(&gcnt[sb[threadIdx.x]], 1.0f);
    }
    for (int i = threadIdx.x; i < m; i += 512) {
        int pk = binned[s + i];
        int nid = pk >> 17;
        int rk = atomicAdd(&cur[nid], 1);
        int pos = lptr[nid] + rk;
        if (pos < LDS_E2) srt[pos] = (pk & 0x1FFFF) << 6;   // byte offset
    }
    __syncthreads();

    int wave = threadIdx.x >> 6;
    int lane = threadIdx.x & 63;
    int sub = lane >> 4;                // subset: owns one node at a time
    int lc  = lane & 15;                // lane-in-subset: cols 4lc..4lc+3
    int l4  = lc << 2;                  // byte offset of that dword in a row
    const unsigned char* xbl = xws + l4;
    int g0 = sb[0];
    float4 bia = ((const float4*)bg)[lc];

#pragma unroll
    for (int r = 0; r < 2; r++) {
        int ln = wave * 8 + sub * 2 + r;          // 32 processors x 2 rounds
        int valid = (ln < nnodes);
        int s0 = valid ? lptr[ln] : 0;
        int e0 = valid ? lptr[ln + 1] : 0;
        if (s0 > LDS_E2) s0 = LDS_E2;
        if (e0 > LDS_E2) e0 = LDS_E2;             // both multiples of 8
        f32x2 al0 = {0.f,0.f}, ah0 = {0.f,0.f};   // 4 independent chains
        f32x2 al1 = {0.f,0.f}, ah1 = {0.f,0.f};
        for (int i = s0; i < e0; i += 8) {        // divergent across subsets
            int4 ra = *(const int4*)&srt[i];      // subset-uniform broadcast
            int4 rb = *(const int4*)&srt[i + 4];
            unsigned int d0 = *(const unsigned int*)(xbl + ra.x);
            unsigned int d1 = *(const unsigned int*)(xbl + ra.y);
            unsigned int d2 = *(const unsigned int*)(xbl + ra.z);
            unsigned int d3 = *(const unsigned int*)(xbl + ra.w);
            unsigned int d4 = *(const unsigned int*)(xbl + rb.x);
            unsigned int d5 = *(const unsigned int*)(xbl + rb.y);
            unsigned int d6 = *(const unsigned int*)(xbl + rb.z);
            unsigned int d7 = *(const unsigned int*)(xbl + rb.w);
            f32x2 p;
            p = __builtin_amdgcn_cvt_pk_f32_fp8(d0, false); al0 += p;
            p = __builtin_amdgcn_cvt_pk_f32_fp8(d0, true);  ah0 += p;
            p = __builtin_amdgcn_cvt_pk_f32_fp8(d1, false); al1 += p;
            p = __builtin_amdgcn_cvt_pk_f32_fp8(d1, true);  ah1 += p;
            p = __builtin_amdgcn_cvt_pk_f32_fp8(d2, false); al0 += p;
            p = __builtin_amdgcn_cvt_pk_f32_fp8(d2, true);  ah0 += p;
            p = __builtin_amdgcn_cvt_pk_f32_fp8(d3, false); al1 += p;
            p = __builtin_amdgcn_cvt_pk_f32_fp8(d3, true);  ah1 += p;
            p = __builtin_amdgcn_cvt_pk_f32_fp8(d4, false); al0 += p;
            p = __builtin_amdgcn_cvt_pk_f32_fp8(d4, true);  ah0 += p;
            p = __builtin_amdgcn_cvt_pk_f32_fp8(d5, false); al1 += p;
            p = __builtin_amdgcn_cvt_pk_f32_fp8(d5, true);  ah1 += p;
            p = __builtin_amdgcn_cvt_pk_f32_fp8(d6, false); al0 += p;
            p = __builtin_amdgcn_cvt_pk_f32_fp8(d6, true);  ah0 += p;
            p = __builtin_amdgcn_cvt_pk_f32_fp8(d7, false); al1 += p;
            p = __builtin_amdgcn_cvt_pk_f32_fp8(d7, true);  ah1 += p;
        }
        f32x2 alo = al0 + al1, ahi = ah0 + ah1;
        int slot = 99;
        float4 val;
        if (valid) {
            float dn = rsqrtf((float)cnt[ln] + 1.0f);
            val.x = fmaxf(alo[0] * dn + bia.x, 0.f);
            val.y = fmaxf(alo[1] * dn + bia.y, 0.f);
            val.z = fmaxf(ahi[0] * dn + bia.z, 0.f);
            val.w = fmaxf(ahi[1] * dn + bia.w, 0.f);
            slot = sb[ln] - g0;
        }
        // serialize the 4 subsets' pool RMW (same wave -> in-order LDS ops)
#pragma unroll
        for (int ss = 0; ss < 4; ss++) {
            if (sub == ss && slot < 4) {
                float4* pp = (float4*)&pool[wave][slot][l4];
                float4 pv = *pp;
                pv.x += val.x; pv.y += val.y; pv.z += val.z; pv.w += val.w;
                *pp = pv;
            }
        }
        if (slot >= 4 && slot < 99) {             // rare: >4 graphs in window
            float* gp = &gsum[sb[ln] * HID_DIM + l4];
            atomicAdd(gp + 0, val.x); atomicAdd(gp + 1, val.y);
            atomicAdd(gp + 2, val.z); atomicAdd(gp + 3, val.w);
        }
    }
    __syncthreads();

    if (threadIdx.x < 8) {
        float c = gcl[threadIdx.x];
        if (c != 0.f) atomicAdd(&gcnt[g0 + threadIdx.x], c);
    }
    for (int t = threadIdx.x; t < 4 * 64; t += 512) {
        int slot = t >> 6, j = t & 63;
        float v = 0.f;
#pragma unroll
        for (int w2 = 0; w2 < 8; w2++) v += pool[w2][slot][j];
        if (v != 0.f) atomicAdd(&gsum[(g0 + slot) * HID_DIM + j], v);
    }
}

// ---- divide by counts + MLP + sigmoid (one wave per graph) ---------------
__global__ __launch_bounds__(64) void k_mlp(const float* __restrict__ gsum,
                                            const float* __restrict__ gcnt,
                                            const float* __restrict__ W1,
                                            const float* __restrict__ b1,
                                            const float* __restrict__ W2,
                                            const float* __restrict__ b2,
                                            float* __restrict__ out) {
    int g = blockIdx.x;
    int j = threadIdx.x;
    float cnt = fmaxf(gcnt[g], 1.0f);

    __shared__ float gs[64];
    __shared__ float hs[64];
    gs[j] = gsum[g * 64 + j] / cnt;
    __syncthreads();

    float h = b1[j];
    for (int k = 0; k < 64; k++) h += gs[k] * W1[k * 64 + j];
    hs[j] = fmaxf(h, 0.f);
    __syncthreads();

    if (j < OUT_DIM) {
        float o = b2[j];
        for (int k = 0; k < 64; k++) o += hs[k] * W2[k * OUT_DIM + j];
        out[g * OUT_DIM + j] = 1.f / (1.f + expf(-o));
    }
}

extern "C" void kernel_launch(void* const* d_in, const int* in_sizes, int n_in,
                              void* d_out, int out_size, void* d_ws, size_t ws_size,
                              hipStream_t stream) {
    const float* x   = (const float*)d_in[0];
    const int* eidx  = (const int*)d_in[1];
    const int* batch = (const int*)d_in[2];
    const float* Wg  = (const float*)d_in[3];
    const float* bg  = (const float*)d_in[4];
    const float* W1  = (const float*)d_in[5];
    const float* b1  = (const float*)d_in[6];
    const float* W2  = (const float*)d_in[7];
    const float* b2  = (const float*)d_in[8];
    float* out = (float*)d_out;

    // workspace layout (~24 MB)
    char* w = (char*)d_ws;
    unsigned char* xws = (unsigned char*)w;     w += (size_t)(N_NODES + 1) * HID_DIM;    // 6.4 MB (fp8)
    int*   binned  = (int*)w;                   w += (size_t)N_EDGES * 4;                // 12.8 MB
    int*   H       = (int*)w;                   w += (size_t)NBUCK * NB3 * 4;            // 1.6 MB
    int*   OFF     = (int*)w;                   w += (size_t)NBUCK * NB3 * 4;            // 1.6 MB
    int*   bsum    = (int*)w;                   w += NSB * 4;
    int*   degs    = (int*)w;                   w += N_NODES * 4;
    float* dinv    = (float*)w;                 w += N_NODES * 4;
    float* gsum    = (float*)w;                 w += N_GRAPHS * HID_DIM * 4;             // 131 KB
    float* gcnt    = (float*)w;                 w += N_GRAPHS * 4;                       // 2 KB

    const int* rowp = eidx;             // edge_index[0] (sources)
    const int* colp = eidx + N_EDGES;   // edge_index[1] (destinations)

    k_hist<<<NB3, 512, 0, stream>>>(colp, H);
    k_scan_a<<<NSB, 1024, 0, stream>>>(H, OFF, bsum);
    k_scan_b<<<NSB, 1024, 0, stream>>>(OFF, bsum, gsum, gcnt, xws);
    k_scatter<<<NB3, 512, 0, stream>>>(rowp, colp, OFF, binned);
    k_deg<<<NBUCK, 256, 0, stream>>>(binned, OFF, degs, dinv);
    k_gemm<<<(N_NODES + 63) / 64, 256, 0, stream>>>(x, Wg, dinv, xws);
    k_aggrf<<<NBUCK, 512, 0, stream>>>(xws, binned, OFF, degs, batch, bg, gsum, gcnt);
    k_mlp<<<N_GRAPHS, 64, 0, stream>>>(gsum, gcnt, W1, b1, W2, b2, out);
}